// Round 6
// baseline (1698.678 us; speedup 1.0000x reference)
//
#include <hip/hip_runtime.h>

// ---------------- problem constants ----------------
constexpr int NY = 100, NX = 200;
constexpr int PML = 35;
constexpr int NYP = 170, NXP = 270;          // padded grid
constexpr int S = 2, NREC = 100, NT = 300;
constexpr float DX = 10.0f, DT = 1e-3f, DT2 = DT * DT;

// tiling: 2 shots x 8x8 tiles -> 128 blocks
constexpr int NTY = 8, NTX = 8;
constexpr int TY = 22, TX = 34;              // nominal tile (last row/col smaller)
constexpr int NBLKS = S * NTY * NTX;         // 128
constexpr int THREADS = 512;

constexpr int UW = TX + 17;                  // 51 (odd): u LDS row stride, 8-halo each side
constexpr int UH = TY + 16;                  // 38
constexpr int PYH = TY + 8;                  // 30: py on +/-4-row apron
constexpr int PXW = TX + 8;                  // 42: px on +/-4-col apron

// global staging strips (u only; py/px never exchanged)
constexpr int STRIDE_NS = 8 * TX;            // 272
constexpr int STRIDE_WE = TY * 8;            // 176
constexpr int STAGE_STRIDE = 2 * STRIDE_NS + 2 * STRIDE_WE;  // 896
constexpr int OFF_N = 0, OFF_S = STRIDE_NS;
constexpr int OFF_W = 2 * STRIDE_NS, OFF_E = 2 * STRIDE_NS + STRIDE_WE;

// stencil coefficients, offsets -4..4, pre-scaled by 1/dx^2 and 1/dx
__device__ __constant__ float C2D[9] = {
    (float)(-1.0/560.0/100.0), (float)(8.0/315.0/100.0), (float)(-1.0/5.0/100.0),
    (float)(8.0/5.0/100.0),    (float)(-205.0/72.0/100.0), (float)(8.0/5.0/100.0),
    (float)(-1.0/5.0/100.0),   (float)(8.0/315.0/100.0),  (float)(-1.0/560.0/100.0)};
__device__ __constant__ float C1D[9] = {
    (float)(1.0/280.0/10.0), (float)(-4.0/105.0/10.0), (float)(1.0/5.0/10.0),
    (float)(-4.0/5.0/10.0),  0.0f,                     (float)(4.0/5.0/10.0),
    (float)(-1.0/5.0/10.0),  (float)(4.0/105.0/10.0),  (float)(-1.0/280.0/10.0)};

// ---------------- L1/L2-bypassing accessors (coherent at Infinity Cache) ----
__device__ __forceinline__ float gload(const float* p) {
    return __hip_atomic_load(p, __ATOMIC_RELAXED, __HIP_MEMORY_SCOPE_AGENT);
}
__device__ __forceinline__ void gstore(float* p, float v) {
    __hip_atomic_store(p, v, __ATOMIC_RELAXED, __HIP_MEMORY_SCOPE_AGENT);
}
__device__ __forceinline__ int iload(const int* p) {
    return __hip_atomic_load(p, __ATOMIC_RELAXED, __HIP_MEMORY_SCOPE_AGENT);
}
__device__ __forceinline__ void istore(int* p, int v) {
    __hip_atomic_store(p, v, __ATOMIC_RELAXED, __HIP_MEMORY_SCOPE_AGENT);
}

__device__ __forceinline__ float sigma_of(int d, int n, float smax) {
    float r = fmaxf(fmaxf((float)(PML - d) / (float)PML,
                          (float)(d - (n - 1 - PML)) / (float)PML), 0.0f);
    return smax * r * r;
}

// ---------------- setup: vmax -> sigma_max ----------------
__global__ void vmax_kernel(const float* __restrict__ vp, float* __restrict__ cst) {
    __shared__ float red[256];
    float m = 0.0f;
    for (int i = threadIdx.x; i < NY * NX; i += 256) m = fmaxf(m, vp[i]);
    red[threadIdx.x] = m;
    __syncthreads();
    for (int s2 = 128; s2 > 0; s2 >>= 1) {
        if (threadIdx.x < s2) red[threadIdx.x] = fmaxf(red[threadIdx.x], red[threadIdx.x + s2]);
        __syncthreads();
    }
    if (threadIdx.x == 0)
        cst[0] = 3.0f * red[0] * logf(1000.0f) / (2.0f * PML * DX);
}

// ------- persistent LDS-tile kernel, pairwise sync, produce-early pipeline --
__global__ __launch_bounds__(THREADS) void persist_kernel(
    const float* __restrict__ vp, const float* __restrict__ src,
    const int* __restrict__ src_loc, const int* __restrict__ rec_loc,
    float* __restrict__ out, float* __restrict__ stage,
    const float* __restrict__ cst, int* __restrict__ flags) {

    __shared__ float uS[2][UH * UW];      // u(t) / u(t-1)->u(t+1), swap each step
    __shared__ float pyS[PYH * TX];       // py on row apron [-4, rows+4)
    __shared__ float pxS[TY * PXW];       // px on col apron [-4, cols+4)
    __shared__ float eS[TY * TX];         // dt^2 * v^2
    __shared__ float dS[TY * TX];         // 1/(1+0.5*s*dt)
    __shared__ float syS[TY], sxS[TX];
    __shared__ float byS[PYH], bymS[PYH], bxS[PXW], bxmS[PXW];

    const int tid = threadIdx.x;
    const int bid = blockIdx.x;
    const int sh  = bid / (NTY * NTX);
    const int tr  = bid - sh * (NTY * NTX);
    const int tyi = tr / NTX, txi = tr - tyi * NTX;
    const int y0 = tyi * TY, x0 = txi * TX;
    const int rows = min(TY, NYP - y0), cols = min(TX, NXP - x0);
    const float smax = cst[0];

    // zero LDS state (domain-boundary halos stay 0 forever)
    for (int i = tid; i < 2 * UH * UW; i += THREADS) ((float*)uS)[i] = 0.0f;
    for (int i = tid; i < PYH * TX; i += THREADS) pyS[i] = 0.0f;
    for (int i = tid; i < TY * PXW; i += THREADS) pxS[i] = 0.0f;

    if (tid < TY) syS[tid] = sigma_of(y0 + tid, NYP, smax);
    if (tid < TX) sxS[tid] = sigma_of(x0 + tid, NXP, smax);
    if (tid < PYH) {
        int yy = y0 - 4 + tid;
        if (yy >= 0 && yy < NYP) {
            float b = __expf(-sigma_of(yy, NYP, smax) * DT);
            byS[tid] = b; bymS[tid] = b - 1.0f;
        } else { byS[tid] = 0.0f; bymS[tid] = 0.0f; }
    }
    if (tid < PXW) {
        int xx = x0 - 4 + tid;
        if (xx >= 0 && xx < NXP) {
            float b = __expf(-sigma_of(xx, NXP, smax) * DT);
            bxS[tid] = b; bxmS[tid] = b - 1.0f;
        } else { bxS[tid] = 0.0f; bxmS[tid] = 0.0f; }
    }
    for (int i = tid; i < rows * cols; i += THREADS) {
        int rr = i / cols, cc = i - rr * cols;
        int gy = y0 + rr, gx = x0 + cc;
        int vy = min(max(gy - PML, 0), NY - 1), vx = min(max(gx - PML, 0), NX - 1);
        float v = vp[vy * NX + vx];
        eS[rr * TX + cc] = DT2 * v * v;
        float s_ = sigma_of(gy, NYP, smax) + sigma_of(gx, NXP, smax);
        dS[rr * TX + cc] = 1.0f / (1.0f + 0.5f * s_ * DT);
    }

    // source (NSRC == 1 per shot)
    const int sy = src_loc[sh * 2 + 0] + PML, sx = src_loc[sh * 2 + 1] + PML;
    const bool ownSrc = (sy >= y0 && sy < y0 + rows && sx >= x0 && sx < x0 + cols);
    const int sLy = sy - y0, sLx = sx - x0;
    const float* srcRow = src + sh * NT;

    // receiver: thread tid handles global receiver tid (<=1 per thread)
    int recLds = -1, recOut = 0;
    if (tid < S * NREC) {
        int rs = tid / NREC, rr2 = tid - rs * NREC;
        int ry = rec_loc[(rs * NREC + rr2) * 2 + 0] + PML;
        int rx = rec_loc[(rs * NREC + rr2) * 2 + 1] + PML;
        if (rs == sh && ry >= y0 && ry < y0 + rows && rx >= x0 && rx < x0 + cols) {
            recLds = (ry - y0 + 8) * UW + (rx - x0 + 8);
            recOut = rs * NT * NREC + rr2;
        }
    }

    const int bN = (tyi > 0)       ? bid - NTX : -1;
    const int bS = (tyi < NTY - 1) ? bid + NTX : -1;
    const int bW = (txi > 0)       ? bid - 1   : -1;
    const int bE = (txi < NTX - 1) ? bid + 1   : -1;

    const int nStr = (rows + 3) >> 2;
    const int nBTasks = nStr * cols;      // <= 6*34 = 204 < THREADS
    const int nNS = 8 * cols, nWE = rows * 8;

    // prologue: stage pre-zeroed by host memset = u(0) strips; announce them.
    if (tid == 0) istore(&flags[bid], 1);
    __syncthreads();

    int pa = 0;
    for (int t = 0; t < NT; t++) {
        const int par = t & 1;                 // slot holding u(t) strips
        float* uCur = uS[pa];
        float* uN   = uS[pa ^ 1];              // holds um; overwritten with un

        // ---- 1. phase A interior (no halo dep) — overlaps neighbor lag ----
        {
            const int nPyI = (rows - 8) * cols, nPxI = rows * (cols - 8);
            for (int i = tid; i < nPyI + nPxI; i += THREADS) {
                if (i < nPyI) {
                    int a = i / cols, cc = i - a * cols, p = 8 + a;
                    float d1 = 0.0f;
#pragma unroll
                    for (int k = 0; k < 9; k++)
                        if (k != 4) d1 = fmaf(C1D[k], uCur[(p + k) * UW + 8 + cc], d1);
                    pyS[p * TX + cc] = fmaf(byS[p], pyS[p * TX + cc], bymS[p] * d1);
                } else {
                    int j = i - nPyI;
                    int rr = j / (cols - 8), q = 8 + (j - rr * (cols - 8));
                    float d1 = 0.0f;
#pragma unroll
                    for (int k = 0; k < 9; k++)
                        if (k != 4) d1 = fmaf(C1D[k], uCur[(8 + rr) * UW + q + k], d1);
                    pxS[rr * PXW + q] = fmaf(bxS[q], pxS[rr * PXW + q], bxmS[q] * d1);
                }
            }
        }

        // ---- 2. pairwise neighbor poll (flags set early: usually hits) ----
        if (tid < 4) {
            int nb = (tid == 0) ? bN : (tid == 1) ? bS : (tid == 2) ? bW : bE;
            if (nb >= 0) {
                while (iload(&flags[nb]) < t + 1) { }
            }
        }
        __syncthreads();                       // B1

        // ---- 3. read neighbor strips (u(t)) into u halos ----
        if (bN >= 0) {
            const float* nb = stage + (size_t)(bN * 2 + par) * STAGE_STRIDE + OFF_S;
            for (int i = tid; i < nNS; i += THREADS) {
                int r2 = i / cols, c2 = i - r2 * cols;
                uCur[r2 * UW + 8 + c2] = gload(nb + r2 * TX + c2);
            }
        }
        if (bS >= 0) {
            const float* nb = stage + (size_t)(bS * 2 + par) * STAGE_STRIDE + OFF_N;
            for (int i = tid; i < nNS; i += THREADS) {
                int r2 = i / cols, c2 = i - r2 * cols;
                uCur[(8 + rows + r2) * UW + 8 + c2] = gload(nb + r2 * TX + c2);
            }
        }
        if (bW >= 0) {
            const float* nb = stage + (size_t)(bW * 2 + par) * STAGE_STRIDE + OFF_E;
            for (int i = tid; i < nWE; i += THREADS)
                uCur[(8 + (i >> 3)) * UW + (i & 7)] = gload(nb + i);
        }
        if (bE >= 0) {
            const float* nb = stage + (size_t)(bE * 2 + par) * STAGE_STRIDE + OFF_W;
            for (int i = tid; i < nWE; i += THREADS)
                uCur[(8 + (i >> 3)) * UW + 8 + cols + (i & 7)] = gload(nb + i);
        }
        __syncthreads();                       // B2

        // ---- 4. phase A border (needs fresh halo) ----
        {
            const int n0 = 8 * cols, n2 = rows * 8;
            for (int i = tid; i < 2 * n0 + 2 * n2; i += THREADS) {
                int j = i, p = -1, cc = 0, q = 0, rr = 0;
                if (j < n0)              { int a = j / cols; p = a;        cc = j - a * cols; }
                else if ((j -= n0) < n0) { int a = j / cols; p = rows + a; cc = j - a * cols; }
                else if ((j -= n0) < n2) { rr = j >> 3; q = j & 7; }
                else                     { j -= n2; rr = j >> 3; q = cols + (j & 7); }
                if (p >= 0) {
                    float d1 = 0.0f;
#pragma unroll
                    for (int k = 0; k < 9; k++)
                        if (k != 4) d1 = fmaf(C1D[k], uCur[(p + k) * UW + 8 + cc], d1);
                    pyS[p * TX + cc] = fmaf(byS[p], pyS[p * TX + cc], bymS[p] * d1);
                } else {
                    float d1 = 0.0f;
#pragma unroll
                    for (int k = 0; k < 9; k++)
                        if (k != 4) d1 = fmaf(C1D[k], uCur[(8 + rr) * UW + q + k], d1);
                    pxS[rr * PXW + q] = fmaf(bxS[q], pxS[rr * PXW + q], bxmS[q] * d1);
                }
            }
        }
        __syncthreads();                       // B3

        // ---- 5. phase B: un update, 4-row register blocking ----
        if (tid < nBTasks) {
            const int strip = tid / cols, cc = tid - strip * cols;
            const int yb = strip * 4;
            const int nr = min(4, rows - yb);
            float ucol[12], pycol[12];
#pragma unroll
            for (int i2 = 0; i2 < 12; i2++) ucol[i2] = uCur[(yb + 4 + i2) * UW + 8 + cc];
#pragma unroll
            for (int i2 = 0; i2 < 12; i2++) {
                int p = yb + i2;
                pycol[i2] = (p < rows + 8) ? pyS[p * TX + cc] : 0.0f;
            }
            const float sxv = sxS[cc];
            for (int i2 = 0; i2 < nr; i2++) {
                const int ly = yb + i2;
                float lap = C2D[4] * ucol[i2 + 4];   // row-stencil center term
#pragma unroll
                for (int k = 0; k < 9; k++) lap = fmaf(C2D[k], ucol[i2 + k], lap);
#pragma unroll
                for (int k = 0; k < 9; k++)
                    if (k != 4) {
                        lap = fmaf(C2D[k], uCur[(8 + ly) * UW + 8 + cc - 4 + k], lap);
                        lap = fmaf(C1D[k], pycol[i2 + k], lap);
                        lap = fmaf(C1D[k], pxS[ly * PXW + cc + k], lap);
                    }
                const float syv = syS[ly];
                const float s_ = syv + sxv, pr = syv * sxv;
                const float Av = 2.0f - pr * DT2;
                const float Bv = 1.0f - 0.5f * s_ * DT;
                const float f = (ownSrc && ly == sLy && cc == sLx) ? srcRow[t] : 0.0f;
                const int ci = (8 + ly) * UW + 8 + cc;
                const float umv = uN[ci];
                uN[ci] = (Av * ucol[i2 + 4] - Bv * umv +
                          eS[ly * TX + cc] * (lap + f)) * dS[ly * TX + cc];
            }
        }
        __syncthreads();                       // B4

        // ---- 6. produce-early: push u(t+1) strips now; receivers sample ----
        if (t + 1 < NT) {
            float* sb = stage + (size_t)(bid * 2 + ((t + 1) & 1)) * STAGE_STRIDE;
            for (int i = tid; i < 2 * nNS + 2 * nWE; i += THREADS) {
                int j = i; float v; int off;
                if (j < nNS) {
                    int r2 = j / cols, c2 = j - r2 * cols;
                    v = uN[(8 + r2) * UW + 8 + c2]; off = OFF_N + r2 * TX + c2;
                } else if ((j -= nNS) < nNS) {
                    int r2 = j / cols, c2 = j - r2 * cols;
                    v = uN[(rows + r2) * UW + 8 + c2]; off = OFF_S + r2 * TX + c2;
                } else if ((j -= nNS) < nWE) {
                    int r2 = j >> 3, c2 = j & 7;
                    v = uN[(8 + r2) * UW + 8 + c2]; off = OFF_W + j;
                } else {
                    j -= nWE; int r2 = j >> 3, c2 = j & 7;
                    v = uN[(8 + r2) * UW + cols + c2]; off = OFF_E + j;
                }
                gstore(sb + off, v);
            }
        }
        if (recLds >= 0) out[recOut + t * NREC] = uN[recLds];
        __syncthreads();                       // B5: drains strip stores (vmcnt 0)
        if (tid == 0 && t + 1 < NT) istore(&flags[bid], t + 2);

        pa ^= 1;
    }
}

// ---------------- host launch ----------------
extern "C" void kernel_launch(void* const* d_in, const int* in_sizes, int n_in,
                              void* d_out, int out_size, void* d_ws, size_t ws_size,
                              hipStream_t stream) {
    const float* vp = (const float*)d_in[0];
    const float* src = (const float*)d_in[1];
    const int* src_loc = (const int*)d_in[2];
    const int* rec_loc = (const int*)d_in[3];
    float* out = (float*)d_out;

    float* ws = (float*)d_ws;
    float* cst   = ws;                       // 16 floats
    int*   flags = (int*)(ws + 16);          // NBLKS ints
    float* stage = ws + 16 + NBLKS;          // NBLKS*2*STAGE_STRIDE floats

    // zero cst + flags + stage (stage zeros = u(0) border strips)
    hipMemsetAsync(d_ws, 0,
                   (size_t)(16 + NBLKS + NBLKS * 2 * STAGE_STRIDE) * sizeof(float),
                   stream);
    vmax_kernel<<<1, 256, 0, stream>>>(vp, cst);
    persist_kernel<<<NBLKS, THREADS, 0, stream>>>(
        vp, src, src_loc, rec_loc, out, stage, cst, flags);
}

// Round 9
// 1417.012 us; speedup vs baseline: 1.1988x; 1.1988x over previous
//
#include <hip/hip_runtime.h>

// ---------------- problem constants ----------------
constexpr int NY = 100, NX = 200;
constexpr int PML = 35;
constexpr int NYP = 170, NXP = 270;          // padded grid
constexpr int S = 2, NREC = 100, NT = 300;
constexpr float DX = 10.0f, DT = 1e-3f, DT2 = DT * DT;

// tiling: 2 shots x 8x8 tiles -> 128 blocks (round-6-proven config)
constexpr int NTY = 8, NTX = 8;
constexpr int TY = 22, TX = 34;              // nominal tile (last row/col smaller)
constexpr int NBLKS = S * NTY * NTX;         // 128
constexpr int THREADS = 512;

constexpr int UW = TX + 17;                  // 51 (odd): u LDS row stride, 8-halo each side
constexpr int UH = TY + 16;                  // 38
constexpr int PYH = TY + 8;                  // 30: py on +/-4-row apron
constexpr int PXW = TX + 8;                  // 42: px on +/-4-col apron

// global staging strips (u only; py/px never exchanged)
constexpr int STRIDE_NS = 8 * TX;            // 272
constexpr int STRIDE_WE = TY * 8;            // 176
constexpr int STAGE_STRIDE = 2 * STRIDE_NS + 2 * STRIDE_WE;  // 896
constexpr int OFF_N = 0, OFF_S = STRIDE_NS;
constexpr int OFF_W = 2 * STRIDE_NS, OFF_E = 2 * STRIDE_NS + STRIDE_WE;

// stencil coefficients, offsets -4..4, pre-scaled by 1/dx^2 and 1/dx
__device__ __constant__ float C2D[9] = {
    (float)(-1.0/560.0/100.0), (float)(8.0/315.0/100.0), (float)(-1.0/5.0/100.0),
    (float)(8.0/5.0/100.0),    (float)(-205.0/72.0/100.0), (float)(8.0/5.0/100.0),
    (float)(-1.0/5.0/100.0),   (float)(8.0/315.0/100.0),  (float)(-1.0/560.0/100.0)};
__device__ __constant__ float C1D[9] = {
    (float)(1.0/280.0/10.0), (float)(-4.0/105.0/10.0), (float)(1.0/5.0/10.0),
    (float)(-4.0/5.0/10.0),  0.0f,                     (float)(4.0/5.0/10.0),
    (float)(-1.0/5.0/10.0),  (float)(4.0/105.0/10.0),  (float)(-1.0/280.0/10.0)};

// ---------------- L1/L2-bypassing accessors (coherent at Infinity Cache) ----
__device__ __forceinline__ float gload(const float* p) {
    return __hip_atomic_load(p, __ATOMIC_RELAXED, __HIP_MEMORY_SCOPE_AGENT);
}
__device__ __forceinline__ void gstore(float* p, float v) {
    __hip_atomic_store(p, v, __ATOMIC_RELAXED, __HIP_MEMORY_SCOPE_AGENT);
}
__device__ __forceinline__ int iload(const int* p) {
    return __hip_atomic_load(p, __ATOMIC_RELAXED, __HIP_MEMORY_SCOPE_AGENT);
}
__device__ __forceinline__ void istore(int* p, int v) {
    __hip_atomic_store(p, v, __ATOMIC_RELAXED, __HIP_MEMORY_SCOPE_AGENT);
}

__device__ __forceinline__ float sigma_of(int d, int n, float smax) {
    float r = fmaxf(fmaxf((float)(PML - d) / (float)PML,
                          (float)(d - (n - 1 - PML)) / (float)PML), 0.0f);
    return smax * r * r;
}

// ---------------- setup: vmax -> sigma_max ----------------
__global__ void vmax_kernel(const float* __restrict__ vp, float* __restrict__ cst) {
    __shared__ float red[256];
    float m = 0.0f;
    for (int i = threadIdx.x; i < NY * NX; i += 256) m = fmaxf(m, vp[i]);
    red[threadIdx.x] = m;
    __syncthreads();
    for (int s2 = 128; s2 > 0; s2 >>= 1) {
        if (threadIdx.x < s2) red[threadIdx.x] = fmaxf(red[threadIdx.x], red[threadIdx.x + s2]);
        __syncthreads();
    }
    if (threadIdx.x == 0)
        cst[0] = 3.0f * red[0] * logf(1000.0f) / (2.0f * PML * DX);
}

// ------- persistent LDS-tile kernel, pairwise sync, fused push -------------
__global__ __launch_bounds__(THREADS) void persist_kernel(
    const float* __restrict__ vp, const float* __restrict__ src,
    const int* __restrict__ src_loc, const int* __restrict__ rec_loc,
    float* __restrict__ out, float* __restrict__ stage,
    const float* __restrict__ cst, int* __restrict__ flags) {

    __shared__ float uS[2][UH * UW];      // u(t) / u(t-1)->u(t+1), swap each step
    __shared__ float pyS[PYH * TX];       // py on row apron [-4, rows+4)
    __shared__ float pxS[TY * PXW];       // px on col apron [-4, cols+4)
    __shared__ float eS[TY * TX];         // dt^2 * v^2
    __shared__ float dS[TY * TX];         // 1/(1+0.5*s*dt)
    __shared__ float syS[TY], sxS[TX];
    __shared__ float byS[PYH], bymS[PYH], bxS[PXW], bxmS[PXW];

    const int tid = threadIdx.x;
    const int bid = blockIdx.x;
    const int sh  = bid / (NTY * NTX);
    const int tr  = bid - sh * (NTY * NTX);
    const int tyi = tr / NTX, txi = tr - tyi * NTX;
    const int y0 = tyi * TY, x0 = txi * TX;
    const int rows = min(TY, NYP - y0), cols = min(TX, NXP - x0);
    const float smax = cst[0];

    // zero LDS state (domain-boundary halos stay 0 forever)
    for (int i = tid; i < 2 * UH * UW; i += THREADS) ((float*)uS)[i] = 0.0f;
    for (int i = tid; i < PYH * TX; i += THREADS) pyS[i] = 0.0f;
    for (int i = tid; i < TY * PXW; i += THREADS) pxS[i] = 0.0f;

    if (tid < TY) syS[tid] = sigma_of(y0 + tid, NYP, smax);
    if (tid < TX) sxS[tid] = sigma_of(x0 + tid, NXP, smax);
    if (tid < PYH) {
        int yy = y0 - 4 + tid;
        if (yy >= 0 && yy < NYP) {
            float b = __expf(-sigma_of(yy, NYP, smax) * DT);
            byS[tid] = b; bymS[tid] = b - 1.0f;
        } else { byS[tid] = 0.0f; bymS[tid] = 0.0f; }
    }
    if (tid < PXW) {
        int xx = x0 - 4 + tid;
        if (xx >= 0 && xx < NXP) {
            float b = __expf(-sigma_of(xx, NXP, smax) * DT);
            bxS[tid] = b; bxmS[tid] = b - 1.0f;
        } else { bxS[tid] = 0.0f; bxmS[tid] = 0.0f; }
    }
    for (int i = tid; i < rows * cols; i += THREADS) {
        int rr = i / cols, cc = i - rr * cols;
        int gy = y0 + rr, gx = x0 + cc;
        int vy = min(max(gy - PML, 0), NY - 1), vx = min(max(gx - PML, 0), NX - 1);
        float v = vp[vy * NX + vx];
        eS[rr * TX + cc] = DT2 * v * v;
        float s_ = sigma_of(gy, NYP, smax) + sigma_of(gx, NXP, smax);
        dS[rr * TX + cc] = 1.0f / (1.0f + 0.5f * s_ * DT);
    }

    // source (NSRC == 1 per shot)
    const int sy = src_loc[sh * 2 + 0] + PML, sx = src_loc[sh * 2 + 1] + PML;
    const bool ownSrc = (sy >= y0 && sy < y0 + rows && sx >= x0 && sx < x0 + cols);
    const int sLy = sy - y0, sLx = sx - x0;
    const float* srcRow = src + sh * NT;

    // receiver: thread tid handles global receiver tid (<=1 per thread)
    int recLds = -1, recOut = 0;
    if (tid < S * NREC) {
        int rs = tid / NREC, rr2 = tid - rs * NREC;
        int ry = rec_loc[(rs * NREC + rr2) * 2 + 0] + PML;
        int rx = rec_loc[(rs * NREC + rr2) * 2 + 1] + PML;
        if (rs == sh && ry >= y0 && ry < y0 + rows && rx >= x0 && rx < x0 + cols) {
            recLds = (ry - y0 + 8) * UW + (rx - x0 + 8);
            recOut = rs * NT * NREC + rr2;
        }
    }

    const int bN = (tyi > 0)       ? bid - NTX : -1;
    const int bS = (tyi < NTY - 1) ? bid + NTX : -1;
    const int bW = (txi > 0)       ? bid - 1   : -1;
    const int bE = (txi < NTX - 1) ? bid + 1   : -1;

    const int nStr = (rows + 1) >> 1;     // 2-row strips
    const int nBTasks = nStr * cols;      // <= 11*34 = 374 <= THREADS (one round)
    const int nNS = 8 * cols, nWE = rows * 8;

    // prologue: stage pre-zeroed by host memset = u(0) strips; announce them.
    if (tid == 0) istore(&flags[bid], 1);
    __syncthreads();

    int pa = 0;
    for (int t = 0; t < NT; t++) {
        const int par = t & 1;                 // slot holding u(t) strips
        float* uCur = uS[pa];
        float* uN   = uS[pa ^ 1];              // holds um; overwritten with un

        // ---- 1. phase A interior (no halo dep) — overlaps neighbor lag ----
        {
            const int nPyI = (rows - 8) * cols, nPxI = rows * (cols - 8);
            for (int i = tid; i < nPyI + nPxI; i += THREADS) {
                if (i < nPyI) {
                    int a = i / cols, cc = i - a * cols, p = 8 + a;
                    float d1a = 0.0f, d1b = 0.0f;
#pragma unroll
                    for (int k = 0; k < 4; k++) {
                        d1a = fmaf(C1D[k],     uCur[(p + k)     * UW + 8 + cc], d1a);
                        d1b = fmaf(C1D[k + 5], uCur[(p + k + 5) * UW + 8 + cc], d1b);
                    }
                    pyS[p * TX + cc] = fmaf(byS[p], pyS[p * TX + cc], bymS[p] * (d1a + d1b));
                } else {
                    int j = i - nPyI;
                    int rr = j / (cols - 8), q = 8 + (j - rr * (cols - 8));
                    float d1a = 0.0f, d1b = 0.0f;
#pragma unroll
                    for (int k = 0; k < 4; k++) {
                        d1a = fmaf(C1D[k],     uCur[(8 + rr) * UW + q + k],     d1a);
                        d1b = fmaf(C1D[k + 5], uCur[(8 + rr) * UW + q + k + 5], d1b);
                    }
                    pxS[rr * PXW + q] = fmaf(bxS[q], pxS[rr * PXW + q], bxmS[q] * (d1a + d1b));
                }
            }
        }

        // ---- 2. pairwise neighbor poll (flags set early: usually hits) ----
        if (tid < 4) {
            int nb = (tid == 0) ? bN : (tid == 1) ? bS : (tid == 2) ? bW : bE;
            if (nb >= 0) {
                while (iload(&flags[nb]) < t + 1) { }
            }
        }
        __syncthreads();                       // B1

        // ---- 3. read neighbor strips (u(t)) into u halos ----
        if (bN >= 0) {
            const float* nb = stage + (size_t)(bN * 2 + par) * STAGE_STRIDE + OFF_S;
            for (int i = tid; i < nNS; i += THREADS) {
                int r2 = i / cols, c2 = i - r2 * cols;
                uCur[r2 * UW + 8 + c2] = gload(nb + r2 * TX + c2);
            }
        }
        if (bS >= 0) {
            const float* nb = stage + (size_t)(bS * 2 + par) * STAGE_STRIDE + OFF_N;
            for (int i = tid; i < nNS; i += THREADS) {
                int r2 = i / cols, c2 = i - r2 * cols;
                uCur[(8 + rows + r2) * UW + 8 + c2] = gload(nb + r2 * TX + c2);
            }
        }
        if (bW >= 0) {
            const float* nb = stage + (size_t)(bW * 2 + par) * STAGE_STRIDE + OFF_E;
            for (int i = tid; i < nWE; i += THREADS)
                uCur[(8 + (i >> 3)) * UW + (i & 7)] = gload(nb + i);
        }
        if (bE >= 0) {
            const float* nb = stage + (size_t)(bE * 2 + par) * STAGE_STRIDE + OFF_W;
            for (int i = tid; i < nWE; i += THREADS)
                uCur[(8 + (i >> 3)) * UW + 8 + cols + (i & 7)] = gload(nb + i);
        }
        __syncthreads();                       // B2

        // ---- 4. phase A border (needs fresh halo) ----
        {
            const int n0 = 8 * cols, n2 = rows * 8;
            for (int i = tid; i < 2 * n0 + 2 * n2; i += THREADS) {
                int j = i, p = -1, cc = 0, q = 0, rr = 0;
                if (j < n0)              { int a = j / cols; p = a;        cc = j - a * cols; }
                else if ((j -= n0) < n0) { int a = j / cols; p = rows + a; cc = j - a * cols; }
                else if ((j -= n0) < n2) { rr = j >> 3; q = j & 7; }
                else                     { j -= n2; rr = j >> 3; q = cols + (j & 7); }
                if (p >= 0) {
                    float d1a = 0.0f, d1b = 0.0f;
#pragma unroll
                    for (int k = 0; k < 4; k++) {
                        d1a = fmaf(C1D[k],     uCur[(p + k)     * UW + 8 + cc], d1a);
                        d1b = fmaf(C1D[k + 5], uCur[(p + k + 5) * UW + 8 + cc], d1b);
                    }
                    pyS[p * TX + cc] = fmaf(byS[p], pyS[p * TX + cc], bymS[p] * (d1a + d1b));
                } else {
                    float d1a = 0.0f, d1b = 0.0f;
#pragma unroll
                    for (int k = 0; k < 4; k++) {
                        d1a = fmaf(C1D[k],     uCur[(8 + rr) * UW + q + k],     d1a);
                        d1b = fmaf(C1D[k + 5], uCur[(8 + rr) * UW + q + k + 5], d1b);
                    }
                    pxS[rr * PXW + q] = fmaf(bxS[q], pxS[rr * PXW + q], bxmS[q] * (d1a + d1b));
                }
            }
        }
        __syncthreads();                       // B3

        // ---- 5. phase B: un update, 2-row tasks, 4 accumulators, fused push
        float* sb = stage + (size_t)(bid * 2 + ((t + 1) & 1)) * STAGE_STRIDE;
        if (tid < nBTasks) {
            const int sy2 = tid / cols, cc = tid - sy2 * cols;
            const int yb = 2 * sy2;
            const int nr = min(2, rows - yb);
            float ucol[10], pycol[10];
#pragma unroll
            for (int i2 = 0; i2 < 10; i2++) ucol[i2] = uCur[(yb + 4 + i2) * UW + 8 + cc];
#pragma unroll
            for (int i2 = 0; i2 < 10; i2++) pycol[i2] = pyS[(yb + i2) * TX + cc];
            const float sxv = sxS[cc];
            for (int i2 = 0; i2 < nr; i2++) {
                const int ly = yb + i2;
                float d2y = 0.0f, d2x = 0.0f, d1py = 0.0f, d1px = 0.0f;
                const float* urow = &uCur[(8 + ly) * UW + 8 + cc - 4];
                const float* pxrow = &pxS[ly * PXW + cc];
#pragma unroll
                for (int k = 0; k < 9; k++) {
                    d2y = fmaf(C2D[k], ucol[i2 + k], d2y);
                    d2x = fmaf(C2D[k], urow[k], d2x);
                    if (k != 4) {
                        d1py = fmaf(C1D[k], pycol[i2 + k], d1py);
                        d1px = fmaf(C1D[k], pxrow[k], d1px);
                    }
                }
                const float lap = (d2y + d2x) + (d1py + d1px);
                const float syv = syS[ly];
                const float s_ = syv + sxv, pr = syv * sxv;
                const float Av = 2.0f - pr * DT2;
                const float Bv = 1.0f - 0.5f * s_ * DT;
                const float f = (ownSrc && ly == sLy && cc == sLx) ? srcRow[t] : 0.0f;
                const int ci = (8 + ly) * UW + 8 + cc;
                const float umv = uN[ci];
                const float unv = (Av * ucol[i2 + 4] - Bv * umv +
                                   eS[ly * TX + cc] * (lap + f)) * dS[ly * TX + cc];
                uN[ci] = unv;
                // fused strip push (u(t+1) ring cells, from register)
                if (ly < 8)          gstore(sb + OFF_N + ly * TX + cc, unv);
                if (ly >= rows - 8)  gstore(sb + OFF_S + (ly - (rows - 8)) * TX + cc, unv);
                if (cc < 8)          gstore(sb + OFF_W + ly * 8 + cc, unv);
                if (cc >= cols - 8)  gstore(sb + OFF_E + ly * 8 + (cc - (cols - 8)), unv);
            }
        }
        __syncthreads();                       // B4: drains strip stores (vmcnt 0)
        if (tid == 0 && t + 1 < NT) istore(&flags[bid], t + 2);

        // ---- 6. receivers sample un ----
        if (recLds >= 0) out[recOut + t * NREC] = uN[recLds];

        pa ^= 1;
    }
}

// ---------------- host launch ----------------
extern "C" void kernel_launch(void* const* d_in, const int* in_sizes, int n_in,
                              void* d_out, int out_size, void* d_ws, size_t ws_size,
                              hipStream_t stream) {
    const float* vp = (const float*)d_in[0];
    const float* src = (const float*)d_in[1];
    const int* src_loc = (const int*)d_in[2];
    const int* rec_loc = (const int*)d_in[3];
    float* out = (float*)d_out;

    float* ws = (float*)d_ws;
    float* cst   = ws;                       // 16 floats
    int*   flags = (int*)(ws + 16);          // NBLKS ints
    float* stage = ws + 16 + NBLKS;          // NBLKS*2*STAGE_STRIDE floats

    // zero cst + flags + stage (stage zeros = u(0) border strips)
    hipMemsetAsync(d_ws, 0,
                   (size_t)(16 + NBLKS + NBLKS * 2 * STAGE_STRIDE) * sizeof(float),
                   stream);
    vmax_kernel<<<1, 256, 0, stream>>>(vp, cst);
    persist_kernel<<<NBLKS, THREADS, 0, stream>>>(
        vp, src, src_loc, rec_loc, out, stage, cst, flags);
}